// Round 5
// baseline (102.074 us; speedup 1.0000x reference)
//
#include <hip/hip_runtime.h>

// Pointer-generator final distribution, fused, chunked-atomic version.
// out[b,t,v] = p*vocab[b,t,v] (v<V, 0 in pad) + scatter_add((1-p)*attn at ids)
//
// One block per (b,t) row. The row is processed in 5 chunks of 40 KB:
//   stream chunk (nt vocab load, normal store) -> __syncthreads() (drains
//   vmcnt: stores visible at L2) -> issue this chunk's global atomics while
//   the lines are still L2-resident.
// vs round 3 (atomics all at end): per-XCD freshly-written footprint drops
// ~25 MB -> ~5 MB, so the atomic RMWs hit L2 instead of re-fetching HBM.
// Scatter targets are row-local; duplicates accumulate (tf.scatter_nd).

typedef float float4v __attribute__((ext_vector_type(4)));

constexpr int TPB    = 256;
constexpr int CHUNK4 = 2505;   // float4s per chunk; 5*2505 = Vext4 = 12525
constexpr int ITERS  = (CHUNK4 + TPB - 1) / TPB;  // 10

__global__ __launch_bounds__(TPB) void pgn_fused_chunked_kernel(
    const float* __restrict__ vocab,   // [BT, V]
    const float* __restrict__ attn,    // [BT, L]
    const float* __restrict__ pg,      // [BT]
    const int* __restrict__ ids,       // [B, L]
    float* __restrict__ out,           // [BT, Vext]
    int T, int L, int V4, int Vext4) {
  const int row = blockIdx.x;          // 0..B*T-1
  const int tid = threadIdx.x;
  const float p = pg[row];
  const float q = 1.0f - p;
  const int b = row / T;               // scalar once per block

  // Preload this thread's scatter entries (L=400 -> at most 2 per thread).
  const float* __restrict__ arow = attn + (long)row * L;
  const int* __restrict__ irow = ids + (long)b * L;
  int id0 = -1, id1 = -1;
  float s0 = 0.f, s1 = 0.f;
  if (tid < L)       { id0 = irow[tid];       s0 = q * arow[tid]; }
  if (tid + TPB < L) { id1 = irow[tid + TPB]; s1 = q * arow[tid + TPB]; }

  const float4v* __restrict__ vrow =
      reinterpret_cast<const float4v*>(vocab) + (long)row * V4;
  float4v* __restrict__ orow4 =
      reinterpret_cast<float4v*>(out) + (long)row * Vext4;
  float* __restrict__ orowf = out + (long)row * (Vext4 * 4);

  for (int lo4 = 0; lo4 < Vext4; lo4 += CHUNK4) {
    const int hi4 = min(lo4 + CHUNK4, Vext4);

    // Stream: out = p*vocab (zero in the OOV pad). Normal stores keep the
    // chunk's lines in L2 for the atomics below.
    #pragma unroll
    for (int i = 0; i < ITERS; ++i) {
      const int c4 = lo4 + tid + i * TPB;
      if (c4 < hi4) {
        float4v o = (float4v)(0.f);
        if (c4 < V4) o = p * __builtin_nontemporal_load(vrow + c4);
        orow4[c4] = o;
      }
    }

    __syncthreads();  // drain stores to L2 before RMWing the same lines

    // This chunk's scatter-adds: lines just written -> L2-hit RMW.
    const int lof = lo4 * 4, hif = hi4 * 4;
    if (id0 >= lof && id0 < hif) atomicAdd(orowf + id0, s0);
    if (id1 >= lof && id1 < hif) atomicAdd(orowf + id1, s1);
    // No barrier needed before next chunk: disjoint addresses.
  }
}

extern "C" void kernel_launch(void* const* d_in, const int* in_sizes, int n_in,
                              void* d_out, int out_size, void* d_ws, size_t ws_size,
                              hipStream_t stream) {
  const float* vocab = (const float*)d_in[0];   // [B,T,V]
  const float* attn  = (const float*)d_in[1];   // [B,T,L]
  const float* pg    = (const float*)d_in[2];   // [B,T,1]
  const int*   ids   = (const int*)d_in[3];     // [B,L]
  float* out = (float*)d_out;

  const int BT   = in_sizes[2];            // B*T = 1024
  const int V    = in_sizes[0] / BT;       // 50000
  const int L    = in_sizes[1] / BT;       // 400
  const int Vext = out_size / BT;          // 50100
  const int B    = in_sizes[3] / L;        // 16
  const int T    = BT / B;                 // 64

  const int V4 = V / 4, Vext4 = Vext / 4;  // 12500, 12525 (rows 16B-aligned)

  pgn_fused_chunked_kernel<<<BT, TPB, 0, stream>>>(vocab, attn, pg, ids, out,
                                                   T, L, V4, Vext4);
}

// Round 6
// 77.171 us; speedup vs baseline: 1.3227x; 1.3227x over previous
//
#include <hip/hip_runtime.h>

// Pointer-generator final distribution — chunk-per-block, LDS scatter,
// pure-streaming version (no global atomics, no mid-stream barriers).
//
// out[b,t,v] = p*vocab[b,t,v] (v<V, 0 in pad) + scatter_add((1-p)*attn at ids)
//
// Grid = (NCHUNK, BT): each block owns one 40 KB chunk of one row.
//   1) zero LDS chunk
//   2) scatter this row's (1-p)*attn hits landing in [lof,hif) into LDS
//      (LDS atomicAdd; duplicates accumulate, matching tf.scatter_nd)
//   3) barrier (block-start, overlapped by other blocks' streams)
//   4) single uninterrupted stream: out = p*vocab + lds  (nt vocab load)
// No global RMW anywhere; every global access is a pure stream.

typedef float float4v __attribute__((ext_vector_type(4)));

constexpr int TPB    = 256;
constexpr int CHUNK4 = 2505;        // float4s per chunk; 5*2505 = Vext4
constexpr int CHUNKF = CHUNK4 * 4;  // 10020 floats = 40080 B LDS -> 4 blk/CU
constexpr int NCHUNK = 5;

__global__ __launch_bounds__(TPB) void pgn_chunk_lds_kernel(
    const float* __restrict__ vocab,   // [BT, V]
    const float* __restrict__ attn,    // [BT, L]
    const float* __restrict__ pg,      // [BT]
    const int* __restrict__ ids,       // [B, L]
    float* __restrict__ out,           // [BT, Vext]
    int T, int L, int V4, int Vext4) {
  __shared__ float lds[CHUNKF];
  float4v* lds4 = reinterpret_cast<float4v*>(lds);

  const int chunk = blockIdx.x;        // 0..NCHUNK-1
  const int row   = blockIdx.y;        // 0..B*T-1
  const int tid   = threadIdx.x;

  const int lo4 = chunk * CHUNK4;
  const int hi4 = min(lo4 + CHUNK4, Vext4);
  const int lof = lo4 * 4, hif = hi4 * 4;

  const float p = pg[row];
  const float q = 1.0f - p;
  const int b = row / T;               // scalar once per block

  // 1) zero the LDS chunk (40 KB; ~3 us aggregate at LDS BW, overlapped).
  for (int c = tid; c < CHUNK4; c += TPB) lds4[c] = (float4v)(0.f);
  __syncthreads();

  // 2) scatter this row's hits that land in this chunk (~L/NCHUNK of L=400).
  const float* __restrict__ arow = attn + (long)row * L;
  const int* __restrict__ irow = ids + (long)b * L;
  for (int l = tid; l < L; l += TPB) {
    const int id = irow[l];
    if (id >= lof && id < hif) atomicAdd(lds + (id - lof), q * arow[l]);
  }
  __syncthreads();

  // 3+4) one uninterrupted 40 KB stream. Consecutive float4/lane: LDS reads
  // are 2-way bank-aliased (free), global fully coalesced.
  const float4v* __restrict__ vrow =
      reinterpret_cast<const float4v*>(vocab) + (long)row * V4;
  float4v* __restrict__ orow =
      reinterpret_cast<float4v*>(out) + (long)row * Vext4;
  for (int c4 = lo4 + tid; c4 < hi4; c4 += TPB) {
    float4v o = lds4[c4 - lo4];
    if (c4 < V4) o += p * __builtin_nontemporal_load(vrow + c4);
    orow[c4] = o;   // normal store (best-known config from R3 vs R4 A/B)
  }
}

extern "C" void kernel_launch(void* const* d_in, const int* in_sizes, int n_in,
                              void* d_out, int out_size, void* d_ws, size_t ws_size,
                              hipStream_t stream) {
  const float* vocab = (const float*)d_in[0];   // [B,T,V]
  const float* attn  = (const float*)d_in[1];   // [B,T,L]
  const float* pg    = (const float*)d_in[2];   // [B,T,1]
  const int*   ids   = (const int*)d_in[3];     // [B,L]
  float* out = (float*)d_out;

  const int BT   = in_sizes[2];            // B*T = 1024
  const int V    = in_sizes[0] / BT;       // 50000
  const int L    = in_sizes[1] / BT;       // 400
  const int Vext = out_size / BT;          // 50100
  const int B    = in_sizes[3] / L;        // 16
  const int T    = BT / B;                 // 64

  const int V4 = V / 4, Vext4 = Vext / 4;  // 12500, 12525 (rows 16B-aligned)

  dim3 grid(NCHUNK, BT);
  pgn_chunk_lds_kernel<<<grid, TPB, 0, stream>>>(vocab, attn, pg, ids, out,
                                                 T, L, V4, Vext4);
}

// Round 7
// 71.839 us; speedup vs baseline: 1.4209x; 1.0742x over previous
//
#include <hip/hip_runtime.h>

// Pointer-generator final distribution — chunk-per-block, LDS scatter,
// pure-streaming, full-occupancy version.
//
// out[b,t,v] = p*vocab[b,t,v] (v<V, 0 in pad) + scatter_add((1-p)*attn at ids)
//
// Grid = (NCHUNK=10, BT): each block owns one ~20 KB chunk of one row.
//   1) zero LDS chunk
//   2) scatter this row's (1-p)*attn hits landing in [lof,hif) into LDS
//      (LDS atomicAdd; duplicates accumulate, matching tf.scatter_nd)
//   3) barrier (block-start; 7 resident neighbor blocks cover it)
//   4) single uninterrupted stream: out = p*vocab + lds  (nt vocab load)
// No global RMW; every global access is a pure stream. 20048 B LDS ->
// 8 blocks/CU (8 x 20480 = 160 KiB exactly) = 32 waves/CU, max occupancy.

typedef float float4v __attribute__((ext_vector_type(4)));

constexpr int TPB    = 256;
constexpr int CHUNK4 = 1253;        // float4s per chunk; 10*1253 >= Vext4
constexpr int CHUNKF = CHUNK4 * 4;  // 5012 floats = 20048 B LDS
constexpr int NCHUNK = 10;

__global__ __launch_bounds__(TPB) void pgn_chunk_lds_kernel(
    const float* __restrict__ vocab,   // [BT, V]
    const float* __restrict__ attn,    // [BT, L]
    const float* __restrict__ pg,      // [BT]
    const int* __restrict__ ids,       // [B, L]
    float* __restrict__ out,           // [BT, Vext]
    int T, int L, int V4, int Vext4) {
  __shared__ float lds[CHUNKF];
  float4v* lds4 = reinterpret_cast<float4v*>(lds);

  const int chunk = blockIdx.x;        // 0..NCHUNK-1
  const int row   = blockIdx.y;        // 0..B*T-1
  const int tid   = threadIdx.x;

  const int lo4 = chunk * CHUNK4;
  const int hi4 = min(lo4 + CHUNK4, Vext4);
  const int lof = lo4 * 4, hif = hi4 * 4;

  const float p = pg[row];
  const float q = 1.0f - p;
  const int b = row / T;               // scalar once per block

  // 1) zero the LDS chunk (~5 ds_write_b128 iters/thread).
  for (int c = tid; c < CHUNK4; c += TPB) lds4[c] = (float4v)(0.f);
  __syncthreads();

  // 2) scatter this row's hits that land in this chunk (~L/NCHUNK of L=400).
  const float* __restrict__ arow = attn + (long)row * L;
  const int* __restrict__ irow = ids + (long)b * L;
  for (int l = tid; l < L; l += TPB) {
    const int id = irow[l];
    if (id >= lof && id < hif) atomicAdd(lds + (id - lof), q * arow[l]);
  }
  __syncthreads();

  // 3+4) one uninterrupted ~20 KB stream. Consecutive float4/lane: LDS reads
  // 2-way bank-aliased (free), global fully coalesced.
  const float4v* __restrict__ vrow =
      reinterpret_cast<const float4v*>(vocab) + (long)row * V4;
  float4v* __restrict__ orow =
      reinterpret_cast<float4v*>(out) + (long)row * Vext4;
  for (int c4 = lo4 + tid; c4 < hi4; c4 += TPB) {
    float4v o = lds4[c4 - lo4];
    if (c4 < V4) o += p * __builtin_nontemporal_load(vrow + c4);
    orow[c4] = o;   // normal store (best-known from R3/R4/R6 A/Bs)
  }
}

extern "C" void kernel_launch(void* const* d_in, const int* in_sizes, int n_in,
                              void* d_out, int out_size, void* d_ws, size_t ws_size,
                              hipStream_t stream) {
  const float* vocab = (const float*)d_in[0];   // [B,T,V]
  const float* attn  = (const float*)d_in[1];   // [B,T,L]
  const float* pg    = (const float*)d_in[2];   // [B,T,1]
  const int*   ids   = (const int*)d_in[3];     // [B,L]
  float* out = (float*)d_out;

  const int BT   = in_sizes[2];            // B*T = 1024
  const int V    = in_sizes[0] / BT;       // 50000
  const int L    = in_sizes[1] / BT;       // 400
  const int Vext = out_size / BT;          // 50100
  const int B    = in_sizes[3] / L;        // 16
  const int T    = BT / B;                 // 64

  const int V4 = V / 4, Vext4 = Vext / 4;  // 12500, 12525 (rows 16B-aligned)

  dim3 grid(NCHUNK, BT);
  pgn_chunk_lds_kernel<<<grid, TPB, 0, stream>>>(vocab, attn, pg, ids, out,
                                                 T, L, V4, Vext4);
}